// Round 2
// baseline (300.859 us; speedup 1.0000x reference)
//
#include <hip/hip_runtime.h>
#include <math.h>

#define NPTS 16384
#define KNN 16
#define GRES 128                 // grid cells per axis
#define NCELL (GRES * GRES)
#define CAP 16                   // slots per cell (Poisson(1): P(>16) ~ 1e-14)

typedef unsigned long long ull;
typedef __attribute__((ext_vector_type(8))) short  bf16x8;
typedef __attribute__((ext_vector_type(4))) float  f32x4;

__device__ inline unsigned short f2bf(float f) {
    unsigned int u = __float_as_uint(f);
    u += 0x7fffu + ((u >> 16) & 1u);          // round-to-nearest-even
    return (unsigned short)(u >> 16);
}
__device__ inline float bf2f(unsigned short u) {
    return __uint_as_float(((unsigned int)u) << 16);
}

// async 16B global->LDS DMA (wave-uniform LDS base + lane*16; dest must be linear)
__device__ inline void glds16(const void* g, void* l) {
    __builtin_amdgcn_global_load_lds((const __attribute__((address_space(1))) void*)g,
                                     (__attribute__((address_space(3))) void*)l, 16, 0, 0);
}

// ---------------- zero cnt (must precede count_scatter) ----------------
__global__ __launch_bounds__(256) void zero_cnt_kernel(int* __restrict__ cnt)
{
    cnt[blockIdx.x * 256 + threadIdx.x] = 0;
}

// ---------------- count+scatter in one pass (slot buckets) ----------------
// block 0 also zeroes the head-reduce counters (consumed much later, stream-ordered)
__global__ __launch_bounds__(256) void count_scatter_kernel(const float2* __restrict__ c,
    int* __restrict__ cnt, float4* __restrict__ pts, int* __restrict__ hctr)
{
    if (blockIdx.x == 0 && threadIdx.x < 128) hctr[threadIdx.x] = 0;
    const int i = blockIdx.x * 256 + threadIdx.x;
    float2 p = c[i];
    int cx = min(GRES - 1, max(0, (int)(p.x * GRES)));
    int cy = min(GRES - 1, max(0, (int)(p.y * GRES)));
    int cell = cy * GRES + cx;
    int slot = atomicAdd(&cnt[cell], 1);
    if (slot < CAP) {
        float4 v;
        v.x = p.x; v.y = p.y; v.z = __uint_as_float((unsigned int)i); v.w = 0.f;
        pts[cell * CAP + slot] = v;
    }
}

// -------- kNN query (blocks >= 512) + weight prep (blocks 0..511) --------
// wprep rides in the same launch: knn is latency-bound, wprep fills scheduler
// slack; weights are not needed until gemm layer 2 (two dispatches later).
// knn: one wave per query, bitonic top-16 across lanes. ALL shuffles execute
// with full EXEC (shuffles must never sit under divergent control flow).
__global__ __launch_bounds__(256) void knn_wprep_kernel(const float2* __restrict__ c,
    const float4* __restrict__ pts, const int* __restrict__ cnt,
    int* __restrict__ nbr, float* __restrict__ ew, float* __restrict__ dinv,
    const float* __restrict__ W0, const float* __restrict__ W1,
    const float* __restrict__ W2, const float* __restrict__ W3,
    const float* __restrict__ W4,
    unsigned short* __restrict__ D0, unsigned short* __restrict__ D1,
    unsigned short* __restrict__ D2, unsigned short* __restrict__ D3,
    unsigned short* __restrict__ D4)
{
    if (blockIdx.x < 512) {
        // ---- weight prep: W (K x Ncol fp32) -> Wt (Ncol x K bf16) ----
        const int wb = blockIdx.x;
        const float* W; unsigned short* D; int K, bx, by;
        if (wb < 256) {
            const int z = wb >> 6, r = wb & 63;
            bx = r & 7; by = r >> 3; K = 256;
            if (z == 0) { W = W0; D = D0; }
            else if (z == 1) { W = W1; D = D1; }
            else if (z == 2) { W = W2; D = D2; }
            else { W = W3; D = D3; }
        } else {
            const int r = wb - 256;
            bx = r & 15; by = r >> 4; K = 512; W = W4; D = D4;
        }
        const int k0 = bx * 32, n0 = by * 32;
        __shared__ float t[32][33];
        const int tr = threadIdx.x >> 5, tc = threadIdx.x & 31;
#pragma unroll
        for (int i = 0; i < 4; ++i)
            t[tr + i * 8][tc] = W[(size_t)(k0 + tr + i * 8) * K + n0 + tc];
        __syncthreads();
#pragma unroll
        for (int i = 0; i < 4; ++i)
            D[(size_t)(n0 + tr + i * 8) * K + k0 + tc] = f2bf(t[tc][tr + i * 8]);
        return;
    }

    const int lane = threadIdx.x & 63;
    const int qidx = (blockIdx.x - 512) * 4 + (threadIdx.x >> 6);
    const float2 qc = c[qidx];
    const float qx = qc.x, qy = qc.y;
    const int qcx = min(GRES - 1, max(0, (int)(qx * GRES)));
    const int qcy = min(GRES - 1, max(0, (int)(qy * GRES)));

    ull cur = ~0ULL;   // lanes 0..15 will hold top-16 ascending; others INF

    auto process = [&](int ccy, int ccx, bool valid) {
        int s0 = 0, len = 0;
        if (valid && ccy >= 0 && ccy < GRES && ccx >= 0 && ccx < GRES) {
            const int cell = ccy * GRES + ccx;
            s0 = cell * CAP;
            len = min(cnt[cell], CAP);
        }
        int pin = len;                       // inclusive prefix over lanes (full exec)
#pragma unroll
        for (int off = 1; off < 64; off <<= 1) {
            int v = __shfl_up(pin, off, 64);
            pin += (lane >= off) ? v : 0;
        }
        const int T = __shfl(pin, 63, 64);
        const int pex = pin - len;
        for (int b = 0; b < T; b += 64) {
            const int ci = b + lane;
            const int cq = min(ci, T - 1);   // clamp so every lane runs uniformly
            int lo = 0, hi = 63;             // smallest h with pin[h] > cq
#pragma unroll
            for (int it = 0; it < 6; ++it) {
                const int mid = (lo + hi) >> 1;
                const int pm = __shfl(pin, mid, 64);   // full exec
                if (pm > cq) hi = mid; else lo = mid + 1;
            }
            const int cs = __shfl(s0, hi, 64);         // full exec
            const int cb = __shfl(pex, hi, 64);        // full exec
            const int p  = cs + (cq - cb);             // valid slot index for all lanes
            const float4 pp = pts[p];
            const float dx = pp.x - qx, dy = pp.y - qy;
            const float d2 = fmaf(dx, dx, dy * dy);
            const int pidx = (int)__float_as_uint(pp.z);
            ull key = ~0ULL;
            if (ci < T && pidx != qidx)
                key = (((ull)__float_as_uint(d2)) << 32) | (ull)__float_as_uint(pp.z);
            // bitonic sort, 64 lanes ascending (full exec)
#pragma unroll
            for (int k = 2; k <= 64; k <<= 1) {
#pragma unroll
                for (int j = k >> 1; j > 0; j >>= 1) {
                    ull o = __shfl_xor(key, j, 64);
                    bool takeMin = (((lane & k) == 0) == ((lane & j) == 0));
                    ull mn = (o < key) ? o : key;
                    ull mx = (o > key) ? o : key;
                    key = takeMin ? mn : mx;
                }
            }
            // merge: cur(asc, lanes0-15) ++ batch-top16 reversed (lanes16-31)
            ull rev = __shfl(key, (31 - lane) & 63, 64);   // full exec, hoisted
            ull val = (lane < 16) ? cur : ((lane < 32) ? rev : ~0ULL);
#pragma unroll
            for (int j = 16; j > 0; j >>= 1) {
                ull o = __shfl_xor(val, j, 64);
                ull mn = (o < val) ? o : val;
                ull mx = (o > val) ? o : val;
                val = ((lane & j) == 0) ? mn : mx;
            }
            cur = (lane < 16) ? val : ~0ULL;
        }
    };

    // initial 7x7 window (49 cells)
    process(qcy - 3 + lane / 7, qcx - 3 + (lane % 7), lane < 49);

    int R = 3;
    const float h = 1.0f / GRES;
    while (true) {
        ull k15 = __shfl(cur, 15, 64);
        float dmax = __uint_as_float((unsigned int)(k15 >> 32)); // NaN if unfilled
        float rr = 0.999f * (float)R * h;
        if (dmax < rr * rr) break;        // NaN -> false -> expand
        if (R >= GRES) break;
        ++R;
        const int ncells = 8 * R;
        for (int cc = 0; cc < ncells; cc += 64) {
            const int i = cc + lane;
            int ccy = 0, ccx = 0;
            const bool valid = (i < ncells);
            if (valid) {
                const int side = 2 * R + 1;
                if (i < side)            { ccy = qcy - R; ccx = qcx - R + i; }
                else if (i < 2 * side)   { ccy = qcy + R; ccx = qcx - R + (i - side); }
                else {
                    const int j = i - 2 * side;
                    ccy = qcy - R + 1 + (j >> 1);
                    ccx = (j & 1) ? (qcx + R) : (qcx - R);
                }
            }
            process(ccy, ccx, valid);
        }
    }

    // epilogue: lanes 0..15 hold the exact top-16 (ascending keys)
    float w = 0.f; int nb = 0;
    if (lane < 16) {
        nb = (int)(cur & 0xffffffffu);
        float d2 = __uint_as_float((unsigned int)(cur >> 32));
        w = expf(-0.5f * sqrtf(d2));
    }
    float acc = w;
#pragma unroll
    for (int off = 1; off < 64; off <<= 1) acc += __shfl_xor(acc, off, 64);
    if (lane < 16) {
        nbr[qidx * KNN + lane] = nb;
        ew[qidx * KNN + lane]  = w;
    }
    if (lane == 0) dinv[qidx] = 1.0f / sqrtf(1.0f + acc);
}

// ----- fused: blocks [0,256): m1 = (x@Wa+ba)+relu(x@Wf1+bf1); [256,512): g1 -----
__global__ __launch_bounds__(256) void init_fused_kernel(
    const float* __restrict__ x, const float2* __restrict__ c,
    const int* __restrict__ nbr, const float* __restrict__ ew, const float* __restrict__ dinv,
    const float* __restrict__ Wa, const float* __restrict__ ba,
    const float* __restrict__ Wf, const float* __restrict__ bf,
    const float* __restrict__ Wc, const float* __restrict__ bc,
    const float* __restrict__ Wg, const float* __restrict__ bg,
    float* __restrict__ m1f, unsigned short* __restrict__ m1b,
    float* __restrict__ g1f, unsigned short* __restrict__ g1b)
{
    __shared__ float smem[64 * 32];
    const int tid = threadIdx.x;
    if (blockIdx.x < 256) {
        const int i0 = blockIdx.x * 64;
#pragma unroll
        for (int it = 0; it < 8; ++it)
            smem[tid + it * 256] = x[(size_t)i0 * 32 + tid + it * 256];
        float wa[32], wf[32];
#pragma unroll
        for (int k = 0; k < 32; ++k) { wa[k] = Wa[k * 256 + tid]; wf[k] = Wf[k * 256 + tid]; }
        const float b0 = ba[tid], b1 = bf[tid];
        __syncthreads();
        for (int r = 0; r < 64; ++r) {
            float a0 = b0, a1 = b1;
#pragma unroll
            for (int k = 0; k < 32; ++k) {
                float xv = smem[r * 32 + k];
                a0 = fmaf(xv, wa[k], a0);
                a1 = fmaf(xv, wf[k], a1);
            }
            const float v = a0 + fmaxf(a1, 0.0f);
            m1f[(size_t)(i0 + r) * 256 + tid] = v;
            m1b[(size_t)(i0 + r) * 256 + tid] = f2bf(v);
        }
    } else {
        float (*su)[5] = (float(*)[5])smem;
        const int i0 = (blockIdx.x - 256) * 64;
        if (tid < 64) {
            const int i = i0 + tid;
            float ux = 0.f, uy = 0.f;
            for (int t = 0; t < KNN; ++t) {
                int nb = nbr[i * KNN + t];
                float w = ew[i * KNN + t] * dinv[nb];
                float2 cn = c[nb];
                ux = fmaf(w, cn.x, ux); uy = fmaf(w, cn.y, uy);
            }
            float di = dinv[i];
            float2 ci = c[i];
            ux = fmaf(di, ci.x, ux); uy = fmaf(di, ci.y, uy);
            su[tid][0] = ux; su[tid][1] = uy; su[tid][2] = ci.x; su[tid][3] = ci.y; su[tid][4] = di;
        }
        __syncthreads();
        const float wc0 = Wc[tid], wc1 = Wc[256 + tid];
        const float wg0 = Wg[tid], wg1 = Wg[256 + tid];
        const float bcj = bc[tid], bgj = bg[tid];
        for (int r = 0; r < 64; ++r) {
            float ux = su[r][0], uy = su[r][1], cx = su[r][2], cy = su[r][3], di = su[r][4];
            float coords0 = fmaf(cx, wc0, fmaf(cy, wc1, bcj));
            float pre = fmaf(di, fmaf(ux, wg0, uy * wg1), bgj);
            const float v = coords0 + fmaxf(pre, 0.0f);
            g1f[(size_t)(i0 + r) * 256 + tid] = v;
            g1b[(size_t)(i0 + r) * 256 + tid] = f2bf(v);
        }
    }
}

// ---------- GCN aggregate (vectorized bf16x8 gather): out = res + relu(b + di*(sum + di*hw_i)) ----------
// 8 rows x 32 col-groups per block; each thread owns 8 consecutive cols (16B loads).
// Half-wave (32 lanes) reads one full 512B hw row contiguously per gather.
__global__ __launch_bounds__(256) void agg_kernel(const unsigned short* __restrict__ hw,
    const int* __restrict__ nbr, const float* __restrict__ ew, const float* __restrict__ dinv,
    const float* __restrict__ bias, const float* __restrict__ res,
    float* __restrict__ outf, unsigned short* __restrict__ outb)
{
    __shared__ int   sn[8][16];
    __shared__ float sw[8][16];
    __shared__ float sdi[8];
    const int tid = threadIdx.x;
    const int i0  = blockIdx.x * 8;
    if (tid < 128) {
        const int r = tid >> 4, t = tid & 15;
        const int i = i0 + r;
        const int nb = nbr[i * KNN + t];
        sn[r][t] = nb;
        sw[r][t] = ew[i * KNN + t] * dinv[nb];
        if (t == 0) sdi[r] = dinv[i];
    }
    __syncthreads();
    const int rl = tid >> 5;          // row within block (broadcast LDS reads, free)
    const int c0 = (tid & 31) * 8;    // 8-col group
    const int i  = i0 + rl;
    const float di = sdi[rl];
    float acc[8];
    {
        const bf16x8 h = *(const bf16x8*)&hw[(size_t)i * 256 + c0];
#pragma unroll
        for (int e = 0; e < 8; ++e) acc[e] = di * bf2f((unsigned short)h[e]);
    }
#pragma unroll
    for (int t = 0; t < KNN; ++t) {
        const float w = sw[rl][t];
        const bf16x8 h = *(const bf16x8*)&hw[(size_t)sn[rl][t] * 256 + c0];
#pragma unroll
        for (int e = 0; e < 8; ++e) acc[e] = fmaf(w, bf2f((unsigned short)h[e]), acc[e]);
    }
    float bb[8], rv[8], vo[8];
    *(float4*)&bb[0] = *(const float4*)&bias[c0];
    *(float4*)&bb[4] = *(const float4*)&bias[c0 + 4];
    *(float4*)&rv[0] = *(const float4*)&res[(size_t)i * 256 + c0];
    *(float4*)&rv[4] = *(const float4*)&res[(size_t)i * 256 + c0 + 4];
    bf16x8 ob;
#pragma unroll
    for (int e = 0; e < 8; ++e) {
        float v = fmaf(di, acc[e], bb[e]);
        v = rv[e] + fmaxf(v, 0.0f);
        vo[e] = v;
        ob[e] = (short)f2bf(v);
    }
    *(float4*)&outf[(size_t)i * 256 + c0]     = *(const float4*)&vo[0];
    *(float4*)&outf[(size_t)i * 256 + c0 + 4] = *(const float4*)&vo[4];
    *(bf16x8*)&outb[(size_t)i * 256 + c0] = ob;
}

// -------- bf16 MFMA GEMM, dual-op (blockIdx.z selects) + head-reduce mode --------
// A row-stride 256 bf16 (split A1|A2 at ksplit). Wt pre-transposed bf16 [n][Kdim].
// Tile 128x128, BK=64, 4 waves (2x2), wave = 4x4 of 16x16x32. fp32 accumulate.
// Staging: double-buffered LDS via global_load_lds width=16 (async DMA). LDS dest
// LINEAR (glds requirement); k-slot XOR swizzle slot' = slot ^ (row&7) applied on
// the SOURCE address and mirrored on the ds_read side (<=2-way alias, free m136).
// flags: 1=+bias 2=relu 4=+res(fp32) 8=write outf 16=write outb
//        32=head-reduce: partial h@Wd2 -> part[(blockIdx.y*2+wc)][row][2]; the
//        LAST block per bx (agent-scope acq-rel counter hctr[bx]) then sums all
//        8 slots and writes mean/sigma directly (finish fused; rows = bx*128..+127).
struct GemmOp {
    const unsigned short *A1, *A2; int ksplit;
    const unsigned short *Wt; int ncols, Kdim;
    const float *bias; const float *res;
    float *outf; unsigned short *outb;
    const float *Wd2; float *part;
    int *hctr; float *meanp; float *sigmap; const float *bd2;
    int flags;
};
__global__ __launch_bounds__(256) void gemm_bf16_kernel(GemmOp opA, GemmOp opB)
{
    const GemmOp op = (blockIdx.z == 0) ? opA : opB;
    __shared__ unsigned short As[2][128 * 64];
    __shared__ unsigned short Bs[2][128 * 64];
    __shared__ int sdone;
    const int tid = threadIdx.x;
    const int r0 = blockIdx.x * 128;
    const int c0 = blockIdx.y * 128;
    const int w  = tid >> 6;
    const int wr = w >> 1, wc = w & 1;
    const int l  = tid & 63;
    const int half = l >> 4, lc = l & 15;

    f32x4 acc[4][4];
#pragma unroll
    for (int mt = 0; mt < 4; ++mt)
#pragma unroll
        for (int nt = 0; nt < 4; ++nt) acc[mt][nt] = (f32x4){0.f, 0.f, 0.f, 0.f};

    // stage one 128x64 A-tile + 128x64 B-tile into buffer b (k-origin k0).
    // linear LDS dest (byte = g*16), source k-slot = (g&7) ^ (row&7).
    auto stage = [&](int b, int k0) {
        const unsigned short* Asrc = (k0 < op.ksplit) ? (op.A1 + k0) : (op.A2 + (k0 - op.ksplit));
        const unsigned short* Bsrc = op.Wt + k0;
#pragma unroll
        for (int it = 0; it < 4; ++it) {
            const int g = tid + it * 256;
            const int r = g >> 3;
            const int s = (g & 7) ^ (r & 7);
            glds16(Asrc + (size_t)(r0 + r) * 256 + s * 8, &As[b][g * 8]);
        }
#pragma unroll
        for (int it = 0; it < 4; ++it) {
            const int g = tid + it * 256;
            const int r = g >> 3;
            const int s = (g & 7) ^ (r & 7);
            glds16(Bsrc + (size_t)(c0 + r) * op.Kdim + s * 8, &Bs[b][g * 8]);
        }
    };

    const int NT = op.Kdim >> 6;
    stage(0, 0);
    __syncthreads();                     // compiler drains vmcnt(0): tile 0 resident
    int cur = 0;
    for (int t = 0; t < NT; ++t) {
        if (t + 1 < NT) stage(cur ^ 1, (t + 1) << 6);   // async, in flight during MFMA
#pragma unroll
        for (int ks = 0; ks < 2; ++ks) {                // k order identical to BK=32 version
            bf16x8 af[4], bq[4];
#pragma unroll
            for (int mt = 0; mt < 4; ++mt) {
                const int rr = wr * 64 + mt * 16 + lc;
                af[mt] = *(const bf16x8*)&As[cur][rr * 64 + ((((ks << 2) + half) ^ (rr & 7)) << 3)];
            }
#pragma unroll
            for (int nt = 0; nt < 4; ++nt) {
                const int rr = wc * 64 + nt * 16 + lc;
                bq[nt] = *(const bf16x8*)&Bs[cur][rr * 64 + ((((ks << 2) + half) ^ (rr & 7)) << 3)];
            }
#pragma unroll
            for (int mt = 0; mt < 4; ++mt)
#pragma unroll
                for (int nt = 0; nt < 4; ++nt)
                    acc[mt][nt] = __builtin_amdgcn_mfma_f32_16x16x32_bf16(af[mt], bq[nt], acc[mt][nt], 0, 0, 0);
        }
        if (t + 1 < NT) { __syncthreads(); cur ^= 1; }  // drain = next tile ready
    }

    // C/D layout: col=lane&15, row=(lane>>4)*4+reg
    if (op.flags & 32) {
        // head-reduce: v = relu(acc+bias); partial dot with Wd2 -> per-(by,wc) slot
        float p0[4][4], p1[4][4];
#pragma unroll
        for (int mt = 0; mt < 4; ++mt)
#pragma unroll
            for (int r = 0; r < 4; ++r) { p0[mt][r] = 0.f; p1[mt][r] = 0.f; }
#pragma unroll
        for (int nt = 0; nt < 4; ++nt) {
            const int col = c0 + wc * 64 + nt * 16 + lc;
            const float bv = op.bias[col];
            const float w0 = op.Wd2[col * 2 + 0];
            const float w1 = op.Wd2[col * 2 + 1];
#pragma unroll
            for (int mt = 0; mt < 4; ++mt)
#pragma unroll
                for (int r = 0; r < 4; ++r) {
                    float v = fmaxf(acc[mt][nt][r] + bv, 0.f);
                    p0[mt][r] = fmaf(v, w0, p0[mt][r]);
                    p1[mt][r] = fmaf(v, w1, p1[mt][r]);
                }
        }
        // reduce over the 16 lanes (lc) sharing each row; full-exec shuffles
#pragma unroll
        for (int mt = 0; mt < 4; ++mt)
#pragma unroll
            for (int r = 0; r < 4; ++r) {
#pragma unroll
                for (int j = 1; j < 16; j <<= 1) {
                    p0[mt][r] += __shfl_xor(p0[mt][r], j, 64);
                    p1[mt][r] += __shfl_xor(p1[mt][r], j, 64);
                }
            }
        if (lc == 0) {
            float* part = op.part + ((size_t)blockIdx.y * 2 + wc) * NPTS * 2;
#pragma unroll
            for (int mt = 0; mt < 4; ++mt) {
                const int rowb = r0 + wr * 64 + mt * 16 + half * 4;
#pragma unroll
                for (int r = 0; r < 4; ++r) {
                    part[(size_t)(rowb + r) * 2 + 0] = p0[mt][r];
                    part[(size_t)(rowb + r) * 2 + 1] = p1[mt][r];
                }
            }
        }
        // ---- fused finish: 4th block to complete this bx sums all 8 slots ----
        __syncthreads();                 // all slot stores issued
        if (tid == 0) {
            __threadfence();             // release our part stores (belt & suspenders)
            sdone = __hip_atomic_fetch_add(op.hctr + blockIdx.x, 1,
                                           __ATOMIC_ACQ_REL, __HIP_MEMORY_SCOPE_AGENT);
        }
        __syncthreads();
        if (sdone == 3) {
            __threadfence();             // acquire: see other blocks' slot stores
            const int row = blockIdx.x * 128 + (tid >> 1);
            const int j = tid & 1;
            float a = 0.f;
#pragma unroll
            for (int s = 0; s < 8; ++s)
                a += op.part[(size_t)s * NPTS * 2 + (size_t)row * 2 + j];
            if (j == 0) {
                op.meanp[row] = a + op.bd2[0];
            } else {
                float z = a + op.bd2[1];
                float sp = fmaxf(z, 0.f) + log1pf(expf(-fabsf(z)));
                op.sigmap[row] = fmaf(0.8f, sp, 0.2f);
            }
        }
        return;
    }
#pragma unroll
    for (int nt = 0; nt < 4; ++nt) {
        const int col = c0 + wc * 64 + nt * 16 + lc;
        const float bv = (op.flags & 1) ? op.bias[col] : 0.f;
#pragma unroll
        for (int mt = 0; mt < 4; ++mt) {
            const int rowb = r0 + wr * 64 + mt * 16 + half * 4;
#pragma unroll
            for (int r = 0; r < 4; ++r) {
                float v = acc[mt][nt][r] + bv;
                if (op.flags & 2) v = fmaxf(v, 0.f);
                if (op.flags & 4) v += op.res[(size_t)(rowb + r) * op.ncols + col];
                if (op.flags & 8)  op.outf[(size_t)(rowb + r) * op.ncols + col] = v;
                if (op.flags & 16) op.outb[(size_t)(rowb + r) * op.ncols + col] = f2bf(v);
            }
        }
    }
}

extern "C" void kernel_launch(void* const* d_in, const int* in_sizes, int n_in,
                              void* d_out, int out_size, void* d_ws, size_t ws_size,
                              hipStream_t stream)
{
    (void)in_sizes; (void)n_in; (void)out_size; (void)ws_size;
    const float* c   = (const float*)d_in[0];
    const float* x   = (const float*)d_in[1];
    const float* Wc  = (const float*)d_in[2];
    const float* bc  = (const float*)d_in[3];
    const float* Wa  = (const float*)d_in[4];
    const float* ba  = (const float*)d_in[5];
    const float* Wg1 = (const float*)d_in[6];
    const float* bg1 = (const float*)d_in[7];
    const float* Wg2 = (const float*)d_in[8];
    const float* bg2 = (const float*)d_in[9];
    const float* Wg3 = (const float*)d_in[10];
    const float* bg3 = (const float*)d_in[11];
    const float* Wf1 = (const float*)d_in[12];
    const float* bf1 = (const float*)d_in[13];
    const float* Wf2 = (const float*)d_in[14];
    const float* bf2 = (const float*)d_in[15];
    const float* Wf3 = (const float*)d_in[16];
    const float* bf3 = (const float*)d_in[17];
    const float* Wd1 = (const float*)d_in[18];
    const float* bd1 = (const float*)d_in[19];
    const float* Wd2 = (const float*)d_in[20];
    const float* bd2 = (const float*)d_in[21];

    float* out = (float*)d_out;
    const size_t N = NPTS;
    const size_t SLOT = N * 256;
    float* wsf  = (float*)d_ws;
    int*   nbr  = (int*)d_ws;            // N*16 ints
    float* ew   = wsf + N * 16;          // N*16
    float* dinv = wsf + N * 32;          // N
    float* s0   = wsf + N * 33;          // m1f
    float* s1   = s0 + SLOT;             // g1f -> g2f (in place)
    float* s2   = s1 + SLOT;             // m2f (grid scratch aliased here pre-GEMM)
    unsigned short* b0 = (unsigned short*)(s2 + SLOT);  // m1b -> m3b
    unsigned short* b1 = b0 + SLOT;                     // g1b -> g2b -> g3b
    unsigned short* b2 = b1 + SLOT;                     // hw2b -> hw3b
    unsigned short* b3 = b2 + SLOT;                     // m2b
    unsigned short* wb = b3 + SLOT;
    unsigned short* bWg2 = wb;                          // 256x256 each
    unsigned short* bWf2 = wb + 65536;
    unsigned short* bWg3 = wb + 131072;
    unsigned short* bWf3 = wb + 196608;
    unsigned short* bWd1 = wb + 262144;                 // 512x512
    float* part = (float*)(wb + 262144 + 262144);       // 8 x N x 2 fp32 head partials
    int* hctr   = (int*)(part + 8 * N * 2);             // 128 head-finish counters

    // kNN grid scratch aliased into s2 (dead before m2f is written)
    float4* g_pts  = (float4*)s2;                 // NCELL*CAP float4 (4 MB)
    int* g_cnt     = (int*)(s2 + (size_t)NCELL * CAP * 4);  // NCELL ints

    float* o_mean  = out;
    float* o_sigma = out + N;
    float* o_g3    = out + 2 * N;
    float* o_m3    = out + 2 * N + N * 256;

    // 1. zero cell counters
    zero_cnt_kernel<<<NCELL / 256, 256, 0, stream>>>(g_cnt);
    // 2. grid build (single pass, slot buckets); block 0 zeroes head counters
    count_scatter_kernel<<<NPTS / 256, 256, 0, stream>>>((const float2*)c, g_cnt, g_pts, hctr);
    // 3. kNN + weight prep (512 wprep blocks lead, knn blocks follow)
    knn_wprep_kernel<<<512 + NPTS / 4, 256, 0, stream>>>((const float2*)c, g_pts, g_cnt,
                                                         nbr, ew, dinv,
                                                         Wg2, Wf2, Wg3, Wf3, Wd1,
                                                         bWg2, bWf2, bWg3, bWf3, bWd1);
    // 4. m1 + g1
    init_fused_kernel<<<512, 256, 0, stream>>>(x, (const float2*)c, nbr, ew, dinv,
                                               Wa, ba, Wf1, bf1, Wc, bc, Wg1, bg1,
                                               s0, b0, s1, b1);

    GemmOp z{};
    // 5. layer 2: hw2 (z=0) & m2 (z=1)
    GemmOp ohw2 = z; ohw2.A1 = b1; ohw2.A2 = b1; ohw2.ksplit = 256; ohw2.Wt = bWg2;
    ohw2.ncols = 256; ohw2.Kdim = 256; ohw2.outb = b2; ohw2.flags = 16;
    GemmOp om2 = z; om2.A1 = b0; om2.A2 = b0; om2.ksplit = 256; om2.Wt = bWf2;
    om2.ncols = 256; om2.Kdim = 256; om2.bias = bf2; om2.res = s0;
    om2.outf = s2; om2.outb = b3; om2.flags = 31;
    gemm_bf16_kernel<<<dim3(NPTS / 128, 2, 2), 256, 0, stream>>>(ohw2, om2);
    // 6. g2 = g1 + relu(agg(hw2) + b_g2) -> s1 (in place) + b1
    agg_kernel<<<NPTS / 8, 256, 0, stream>>>(b2, nbr, ew, dinv, bg2, s1, s1, b1);

    // 7. layer 3: hw3 (z=0) & m3 (z=1)
    GemmOp ohw3 = z; ohw3.A1 = b1; ohw3.A2 = b1; ohw3.ksplit = 256; ohw3.Wt = bWg3;
    ohw3.ncols = 256; ohw3.Kdim = 256; ohw3.outb = b2; ohw3.flags = 16;
    GemmOp om3 = z; om3.A1 = b3; om3.A2 = b3; om3.ksplit = 256; om3.Wt = bWf3;
    om3.ncols = 256; om3.Kdim = 256; om3.bias = bf3; om3.res = s2;
    om3.outf = o_m3; om3.outb = b0; om3.flags = 31;
    gemm_bf16_kernel<<<dim3(NPTS / 128, 2, 2), 256, 0, stream>>>(ohw3, om3);
    // 8. g3 = g2 + relu(agg(hw3) + b_g3) -> o_g3 + b1
    agg_kernel<<<NPTS / 8, 256, 0, stream>>>(b2, nbr, ew, dinv, bg3, s1, o_g3, b1);

    // 9. head: h = relu([g3|m3]@W_d1 + b_d1); partial h@W_d2 -> part slots;
    //    last block per bx fuses the finish (mean/sigma)
    GemmOp oh = z; oh.A1 = b1; oh.A2 = b0; oh.ksplit = 256; oh.Wt = bWd1;
    oh.ncols = 512; oh.Kdim = 512; oh.bias = bd1; oh.Wd2 = Wd2; oh.part = part;
    oh.hctr = hctr; oh.meanp = o_mean; oh.sigmap = o_sigma; oh.bd2 = bd2;
    oh.flags = 32;
    gemm_bf16_kernel<<<dim3(NPTS / 128, 4, 1), 256, 0, stream>>>(oh, oh);
}

// Round 3
// 299.233 us; speedup vs baseline: 1.0054x; 1.0054x over previous
//
#include <hip/hip_runtime.h>
#include <math.h>

#define NPTS 16384
#define KNN 16
#define GRES 128                 // grid cells per axis
#define NCELL (GRES * GRES)
#define CAP 16                   // slots per cell (Poisson(1): P(>16) ~ 1e-14)

typedef unsigned long long ull;
typedef __attribute__((ext_vector_type(8))) short  bf16x8;
typedef __attribute__((ext_vector_type(4))) float  f32x4;

__device__ inline unsigned short f2bf(float f) {
    unsigned int u = __float_as_uint(f);
    u += 0x7fffu + ((u >> 16) & 1u);          // round-to-nearest-even
    return (unsigned short)(u >> 16);
}
__device__ inline float bf2f(unsigned short u) {
    return __uint_as_float(((unsigned int)u) << 16);
}

// async 16B global->LDS DMA (wave-uniform LDS base + lane*16; dest must be linear)
__device__ inline void glds16(const void* g, void* l) {
    __builtin_amdgcn_global_load_lds((const __attribute__((address_space(1))) void*)g,
                                     (__attribute__((address_space(3))) void*)l, 16, 0, 0);
}

// ------- weight prep: W (K x Ncol fp32) -> Wt (Ncol x K bf16); z=5 plane zeroes cnt -------
// (kept as a standalone dispatch: fusing it into the knn launch shares register
//  allocation with the latency-bound knn path and tripped an occupancy cliff
//  there — round-2 regression, +25 us)
__global__ __launch_bounds__(256) void wprep_kernel(
    const float* __restrict__ W0, const float* __restrict__ W1,
    const float* __restrict__ W2, const float* __restrict__ W3,
    const float* __restrict__ W4,
    unsigned short* __restrict__ D0, unsigned short* __restrict__ D1,
    unsigned short* __restrict__ D2, unsigned short* __restrict__ D3,
    unsigned short* __restrict__ D4, int* __restrict__ cnt)
{
    const int z = blockIdx.z;
    if (z == 5) {
        const int i = (blockIdx.y * 16 + blockIdx.x) * 256 + threadIdx.x;
        if (i < NCELL) cnt[i] = 0;
        return;
    }
    const float* W; unsigned short* D; int K;
    if (z == 0) { W = W0; D = D0; K = 256; }
    else if (z == 1) { W = W1; D = D1; K = 256; }
    else if (z == 2) { W = W2; D = D2; K = 256; }
    else if (z == 3) { W = W3; D = D3; K = 256; }
    else { W = W4; D = D4; K = 512; }
    const int nt = K / 32;
    if (blockIdx.x >= nt || blockIdx.y >= nt) return;
    const int k0 = blockIdx.x * 32, n0 = blockIdx.y * 32;
    __shared__ float t[32][33];
    const int tr = threadIdx.x >> 5, tc = threadIdx.x & 31;
#pragma unroll
    for (int i = 0; i < 4; ++i)
        t[tr + i * 8][tc] = W[(size_t)(k0 + tr + i * 8) * K + n0 + tc];
    __syncthreads();
#pragma unroll
    for (int i = 0; i < 4; ++i)
        D[(size_t)(n0 + tr + i * 8) * K + k0 + tc] = f2bf(t[tc][tr + i * 8]);
}

// ---------------- count+scatter in one pass (slot buckets) ----------------
// block 0 also zeroes the head-reduce counters (consumed much later, stream-ordered)
__global__ __launch_bounds__(256) void count_scatter_kernel(const float2* __restrict__ c,
    int* __restrict__ cnt, float4* __restrict__ pts, int* __restrict__ hctr)
{
    if (blockIdx.x == 0 && threadIdx.x < 128) hctr[threadIdx.x] = 0;
    const int i = blockIdx.x * 256 + threadIdx.x;
    float2 p = c[i];
    int cx = min(GRES - 1, max(0, (int)(p.x * GRES)));
    int cy = min(GRES - 1, max(0, (int)(p.y * GRES)));
    int cell = cy * GRES + cx;
    int slot = atomicAdd(&cnt[cell], 1);
    if (slot < CAP) {
        float4 v;
        v.x = p.x; v.y = p.y; v.z = __uint_as_float((unsigned int)i); v.w = 0.f;
        pts[cell * CAP + slot] = v;
    }
}

// -------- kNN query: one wave per query, bitonic top-16 across lanes --------
// ALL shuffles execute with full EXEC (shuffle reads from disabled lanes
// return 0 -> shuffles must never sit under divergent control flow).
__global__ __launch_bounds__(256) void knn_query_kernel(const float2* __restrict__ c,
    const float4* __restrict__ pts, const int* __restrict__ cnt,
    int* __restrict__ nbr, float* __restrict__ ew, float* __restrict__ dinv)
{
    const int lane = threadIdx.x & 63;
    const int qidx = blockIdx.x * 4 + (threadIdx.x >> 6);
    const float2 qc = c[qidx];
    const float qx = qc.x, qy = qc.y;
    const int qcx = min(GRES - 1, max(0, (int)(qx * GRES)));
    const int qcy = min(GRES - 1, max(0, (int)(qy * GRES)));

    ull cur = ~0ULL;   // lanes 0..15 will hold top-16 ascending; others INF

    auto process = [&](int ccy, int ccx, bool valid) {
        int s0 = 0, len = 0;
        if (valid && ccy >= 0 && ccy < GRES && ccx >= 0 && ccx < GRES) {
            const int cell = ccy * GRES + ccx;
            s0 = cell * CAP;
            len = min(cnt[cell], CAP);
        }
        int pin = len;                       // inclusive prefix over lanes (full exec)
#pragma unroll
        for (int off = 1; off < 64; off <<= 1) {
            int v = __shfl_up(pin, off, 64);
            pin += (lane >= off) ? v : 0;
        }
        const int T = __shfl(pin, 63, 64);
        const int pex = pin - len;
        for (int b = 0; b < T; b += 64) {
            const int ci = b + lane;
            const int cq = min(ci, T - 1);   // clamp so every lane runs uniformly
            int lo = 0, hi = 63;             // smallest h with pin[h] > cq
#pragma unroll
            for (int it = 0; it < 6; ++it) {
                const int mid = (lo + hi) >> 1;
                const int pm = __shfl(pin, mid, 64);   // full exec
                if (pm > cq) hi = mid; else lo = mid + 1;
            }
            const int cs = __shfl(s0, hi, 64);         // full exec
            const int cb = __shfl(pex, hi, 64);        // full exec
            const int p  = cs + (cq - cb);             // valid slot index for all lanes
            const float4 pp = pts[p];
            const float dx = pp.x - qx, dy = pp.y - qy;
            const float d2 = fmaf(dx, dx, dy * dy);
            const int pidx = (int)__float_as_uint(pp.z);
            ull key = ~0ULL;
            if (ci < T && pidx != qidx)
                key = (((ull)__float_as_uint(d2)) << 32) | (ull)__float_as_uint(pp.z);
            // bitonic sort, 64 lanes ascending (full exec)
#pragma unroll
            for (int k = 2; k <= 64; k <<= 1) {
#pragma unroll
                for (int j = k >> 1; j > 0; j >>= 1) {
                    ull o = __shfl_xor(key, j, 64);
                    bool takeMin = (((lane & k) == 0) == ((lane & j) == 0));
                    ull mn = (o < key) ? o : key;
                    ull mx = (o > key) ? o : key;
                    key = takeMin ? mn : mx;
                }
            }
            // merge: cur(asc, lanes0-15) ++ batch-top16 reversed (lanes16-31)
            ull rev = __shfl(key, (31 - lane) & 63, 64);   // full exec, hoisted
            ull val = (lane < 16) ? cur : ((lane < 32) ? rev : ~0ULL);
#pragma unroll
            for (int j = 16; j > 0; j >>= 1) {
                ull o = __shfl_xor(val, j, 64);
                ull mn = (o < val) ? o : val;
                ull mx = (o > val) ? o : val;
                val = ((lane & j) == 0) ? mn : mx;
            }
            cur = (lane < 16) ? val : ~0ULL;
        }
    };

    // initial 7x7 window (49 cells)
    process(qcy - 3 + lane / 7, qcx - 3 + (lane % 7), lane < 49);

    int R = 3;
    const float h = 1.0f / GRES;
    while (true) {
        ull k15 = __shfl(cur, 15, 64);
        float dmax = __uint_as_float((unsigned int)(k15 >> 32)); // NaN if unfilled
        float rr = 0.999f * (float)R * h;
        if (dmax < rr * rr) break;        // NaN -> false -> expand
        if (R >= GRES) break;
        ++R;
        const int ncells = 8 * R;
        for (int cc = 0; cc < ncells; cc += 64) {
            const int i = cc + lane;
            int ccy = 0, ccx = 0;
            const bool valid = (i < ncells);
            if (valid) {
                const int side = 2 * R + 1;
                if (i < side)            { ccy = qcy - R; ccx = qcx - R + i; }
                else if (i < 2 * side)   { ccy = qcy + R; ccx = qcx - R + (i - side); }
                else {
                    const int j = i - 2 * side;
                    ccy = qcy - R + 1 + (j >> 1);
                    ccx = (j & 1) ? (qcx + R) : (qcx - R);
                }
            }
            process(ccy, ccx, valid);
        }
    }

    // epilogue: lanes 0..15 hold the exact top-16 (ascending keys)
    float w = 0.f; int nb = 0;
    if (lane < 16) {
        nb = (int)(cur & 0xffffffffu);
        float d2 = __uint_as_float((unsigned int)(cur >> 32));
        w = expf(-0.5f * sqrtf(d2));
    }
    float acc = w;
#pragma unroll
    for (int off = 1; off < 64; off <<= 1) acc += __shfl_xor(acc, off, 64);
    if (lane < 16) {
        nbr[qidx * KNN + lane] = nb;
        ew[qidx * KNN + lane]  = w;
    }
    if (lane == 0) dinv[qidx] = 1.0f / sqrtf(1.0f + acc);
}

// ----- fused: blocks [0,256): m1 = (x@Wa+ba)+relu(x@Wf1+bf1); [256,512): g1 -----
__global__ __launch_bounds__(256) void init_fused_kernel(
    const float* __restrict__ x, const float2* __restrict__ c,
    const int* __restrict__ nbr, const float* __restrict__ ew, const float* __restrict__ dinv,
    const float* __restrict__ Wa, const float* __restrict__ ba,
    const float* __restrict__ Wf, const float* __restrict__ bf,
    const float* __restrict__ Wc, const float* __restrict__ bc,
    const float* __restrict__ Wg, const float* __restrict__ bg,
    float* __restrict__ m1f, unsigned short* __restrict__ m1b,
    float* __restrict__ g1f, unsigned short* __restrict__ g1b)
{
    __shared__ float smem[64 * 32];
    const int tid = threadIdx.x;
    if (blockIdx.x < 256) {
        const int i0 = blockIdx.x * 64;
#pragma unroll
        for (int it = 0; it < 8; ++it)
            smem[tid + it * 256] = x[(size_t)i0 * 32 + tid + it * 256];
        float wa[32], wf[32];
#pragma unroll
        for (int k = 0; k < 32; ++k) { wa[k] = Wa[k * 256 + tid]; wf[k] = Wf[k * 256 + tid]; }
        const float b0 = ba[tid], b1 = bf[tid];
        __syncthreads();
        for (int r = 0; r < 64; ++r) {
            float a0 = b0, a1 = b1;
#pragma unroll
            for (int k = 0; k < 32; ++k) {
                float xv = smem[r * 32 + k];
                a0 = fmaf(xv, wa[k], a0);
                a1 = fmaf(xv, wf[k], a1);
            }
            const float v = a0 + fmaxf(a1, 0.0f);
            m1f[(size_t)(i0 + r) * 256 + tid] = v;
            m1b[(size_t)(i0 + r) * 256 + tid] = f2bf(v);
        }
    } else {
        float (*su)[5] = (float(*)[5])smem;
        const int i0 = (blockIdx.x - 256) * 64;
        if (tid < 64) {
            const int i = i0 + tid;
            float ux = 0.f, uy = 0.f;
            for (int t = 0; t < KNN; ++t) {
                int nb = nbr[i * KNN + t];
                float w = ew[i * KNN + t] * dinv[nb];
                float2 cn = c[nb];
                ux = fmaf(w, cn.x, ux); uy = fmaf(w, cn.y, uy);
            }
            float di = dinv[i];
            float2 ci = c[i];
            ux = fmaf(di, ci.x, ux); uy = fmaf(di, ci.y, uy);
            su[tid][0] = ux; su[tid][1] = uy; su[tid][2] = ci.x; su[tid][3] = ci.y; su[tid][4] = di;
        }
        __syncthreads();
        const float wc0 = Wc[tid], wc1 = Wc[256 + tid];
        const float wg0 = Wg[tid], wg1 = Wg[256 + tid];
        const float bcj = bc[tid], bgj = bg[tid];
        for (int r = 0; r < 64; ++r) {
            float ux = su[r][0], uy = su[r][1], cx = su[r][2], cy = su[r][3], di = su[r][4];
            float coords0 = fmaf(cx, wc0, fmaf(cy, wc1, bcj));
            float pre = fmaf(di, fmaf(ux, wg0, uy * wg1), bgj);
            const float v = coords0 + fmaxf(pre, 0.0f);
            g1f[(size_t)(i0 + r) * 256 + tid] = v;
            g1b[(size_t)(i0 + r) * 256 + tid] = f2bf(v);
        }
    }
}

// ---------- GCN aggregate (vectorized bf16x8 gather): out = res + relu(b + di*(sum + di*hw_i)) ----------
// 8 rows x 32 col-groups per block; each thread owns 8 consecutive cols (16B loads).
// Half-wave (32 lanes) reads one full 512B hw row contiguously per gather.
__global__ __launch_bounds__(256) void agg_kernel(const unsigned short* __restrict__ hw,
    const int* __restrict__ nbr, const float* __restrict__ ew, const float* __restrict__ dinv,
    const float* __restrict__ bias, const float* __restrict__ res,
    float* __restrict__ outf, unsigned short* __restrict__ outb)
{
    __shared__ int   sn[8][16];
    __shared__ float sw[8][16];
    __shared__ float sdi[8];
    const int tid = threadIdx.x;
    const int i0  = blockIdx.x * 8;
    if (tid < 128) {
        const int r = tid >> 4, t = tid & 15;
        const int i = i0 + r;
        const int nb = nbr[i * KNN + t];
        sn[r][t] = nb;
        sw[r][t] = ew[i * KNN + t] * dinv[nb];
        if (t == 0) sdi[r] = dinv[i];
    }
    __syncthreads();
    const int rl = tid >> 5;          // row within block (broadcast LDS reads, free)
    const int c0 = (tid & 31) * 8;    // 8-col group
    const int i  = i0 + rl;
    const float di = sdi[rl];
    float acc[8];
    {
        const bf16x8 h = *(const bf16x8*)&hw[(size_t)i * 256 + c0];
#pragma unroll
        for (int e = 0; e < 8; ++e) acc[e] = di * bf2f((unsigned short)h[e]);
    }
#pragma unroll
    for (int t = 0; t < KNN; ++t) {
        const float w = sw[rl][t];
        const bf16x8 h = *(const bf16x8*)&hw[(size_t)sn[rl][t] * 256 + c0];
#pragma unroll
        for (int e = 0; e < 8; ++e) acc[e] = fmaf(w, bf2f((unsigned short)h[e]), acc[e]);
    }
    float bb[8], rv[8], vo[8];
    *(float4*)&bb[0] = *(const float4*)&bias[c0];
    *(float4*)&bb[4] = *(const float4*)&bias[c0 + 4];
    *(float4*)&rv[0] = *(const float4*)&res[(size_t)i * 256 + c0];
    *(float4*)&rv[4] = *(const float4*)&res[(size_t)i * 256 + c0 + 4];
    bf16x8 ob;
#pragma unroll
    for (int e = 0; e < 8; ++e) {
        float v = fmaf(di, acc[e], bb[e]);
        v = rv[e] + fmaxf(v, 0.0f);
        vo[e] = v;
        ob[e] = (short)f2bf(v);
    }
    *(float4*)&outf[(size_t)i * 256 + c0]     = *(const float4*)&vo[0];
    *(float4*)&outf[(size_t)i * 256 + c0 + 4] = *(const float4*)&vo[4];
    *(bf16x8*)&outb[(size_t)i * 256 + c0] = ob;
}

// -------- bf16 MFMA GEMM, dual-op (blockIdx.z selects) + head-reduce mode --------
// A row-stride 256 bf16 (split A1|A2 at ksplit). Wt pre-transposed bf16 [n][Kdim].
// Tile 128x128, BK=64, 4 waves (2x2), wave = 4x4 of 16x16x32. fp32 accumulate.
// Staging: double-buffered LDS via global_load_lds width=16 (async DMA). LDS dest
// LINEAR (glds requirement); k-slot XOR swizzle slot' = slot ^ (row&7) applied on
// the SOURCE address and mirrored on the ds_read side (<=2-way alias, free m136).
// Occupancy is LDS-bound (64KB -> 2 blocks/CU); the finish path below cannot
// reduce it (VGPR headroom is ample at 2 waves/SIMD).
// flags: 1=+bias 2=relu 4=+res(fp32) 8=write outf 16=write outb
//        32=head-reduce: partial h@Wd2 -> part[(blockIdx.y*2+wc)][row][2]; the
//        LAST block per bx (agent-scope acq-rel counter hctr[bx]) then sums all
//        8 slots and writes mean/sigma directly (finish fused; rows = bx*128..+127).
struct GemmOp {
    const unsigned short *A1, *A2; int ksplit;
    const unsigned short *Wt; int ncols, Kdim;
    const float *bias; const float *res;
    float *outf; unsigned short *outb;
    const float *Wd2; float *part;
    int *hctr; float *meanp; float *sigmap; const float *bd2;
    int flags;
};
__global__ __launch_bounds__(256) void gemm_bf16_kernel(GemmOp opA, GemmOp opB)
{
    const GemmOp op = (blockIdx.z == 0) ? opA : opB;
    __shared__ unsigned short As[2][128 * 64];
    __shared__ unsigned short Bs[2][128 * 64];
    __shared__ int sdone;
    const int tid = threadIdx.x;
    const int r0 = blockIdx.x * 128;
    const int c0 = blockIdx.y * 128;
    const int w  = tid >> 6;
    const int wr = w >> 1, wc = w & 1;
    const int l  = tid & 63;
    const int half = l >> 4, lc = l & 15;

    f32x4 acc[4][4];
#pragma unroll
    for (int mt = 0; mt < 4; ++mt)
#pragma unroll
        for (int nt = 0; nt < 4; ++nt) acc[mt][nt] = (f32x4){0.f, 0.f, 0.f, 0.f};

    // stage one 128x64 A-tile + 128x64 B-tile into buffer b (k-origin k0).
    // linear LDS dest (byte = g*16), source k-slot = (g&7) ^ (row&7).
    auto stage = [&](int b, int k0) {
        const unsigned short* Asrc = (k0 < op.ksplit) ? (op.A1 + k0) : (op.A2 + (k0 - op.ksplit));
        const unsigned short* Bsrc = op.Wt + k0;
#pragma unroll
        for (int it = 0; it < 4; ++it) {
            const int g = tid + it * 256;
            const int r = g >> 3;
            const int s = (g & 7) ^ (r & 7);
            glds16(Asrc + (size_t)(r0 + r) * 256 + s * 8, &As[b][g * 8]);
        }
#pragma unroll
        for (int it = 0; it < 4; ++it) {
            const int g = tid + it * 256;
            const int r = g >> 3;
            const int s = (g & 7) ^ (r & 7);
            glds16(Bsrc + (size_t)(c0 + r) * op.Kdim + s * 8, &Bs[b][g * 8]);
        }
    };

    const int NT = op.Kdim >> 6;
    stage(0, 0);
    __syncthreads();                     // compiler drains vmcnt(0): tile 0 resident
    int cur = 0;
    for (int t = 0; t < NT; ++t) {
        if (t + 1 < NT) stage(cur ^ 1, (t + 1) << 6);   // async, in flight during MFMA
#pragma unroll
        for (int ks = 0; ks < 2; ++ks) {                // k order identical to BK=32 version
            bf16x8 af[4], bq[4];
#pragma unroll
            for (int mt = 0; mt < 4; ++mt) {
                const int rr = wr * 64 + mt * 16 + lc;
                af[mt] = *(const bf16x8*)&As[cur][rr * 64 + ((((ks << 2) + half) ^ (rr & 7)) << 3)];
            }
#pragma unroll
            for (int nt = 0; nt < 4; ++nt) {
                const int rr = wc * 64 + nt * 16 + lc;
                bq[nt] = *(const bf16x8*)&Bs[cur][rr * 64 + ((((ks << 2) + half) ^ (rr & 7)) << 3)];
            }
#pragma unroll
            for (int mt = 0; mt < 4; ++mt)
#pragma unroll
                for (int nt = 0; nt < 4; ++nt)
                    acc[mt][nt] = __builtin_amdgcn_mfma_f32_16x16x32_bf16(af[mt], bq[nt], acc[mt][nt], 0, 0, 0);
        }
        if (t + 1 < NT) { __syncthreads(); cur ^= 1; }  // drain = next tile ready
    }

    // C/D layout: col=lane&15, row=(lane>>4)*4+reg
    if (op.flags & 32) {
        // head-reduce: v = relu(acc+bias); partial dot with Wd2 -> per-(by,wc) slot
        float p0[4][4], p1[4][4];
#pragma unroll
        for (int mt = 0; mt < 4; ++mt)
#pragma unroll
            for (int r = 0; r < 4; ++r) { p0[mt][r] = 0.f; p1[mt][r] = 0.f; }
#pragma unroll
        for (int nt = 0; nt < 4; ++nt) {
            const int col = c0 + wc * 64 + nt * 16 + lc;
            const float bv = op.bias[col];
            const float w0 = op.Wd2[col * 2 + 0];
            const float w1 = op.Wd2[col * 2 + 1];
#pragma unroll
            for (int mt = 0; mt < 4; ++mt)
#pragma unroll
                for (int r = 0; r < 4; ++r) {
                    float v = fmaxf(acc[mt][nt][r] + bv, 0.f);
                    p0[mt][r] = fmaf(v, w0, p0[mt][r]);
                    p1[mt][r] = fmaf(v, w1, p1[mt][r]);
                }
        }
        // reduce over the 16 lanes (lc) sharing each row; full-exec shuffles
#pragma unroll
        for (int mt = 0; mt < 4; ++mt)
#pragma unroll
            for (int r = 0; r < 4; ++r) {
#pragma unroll
                for (int j = 1; j < 16; j <<= 1) {
                    p0[mt][r] += __shfl_xor(p0[mt][r], j, 64);
                    p1[mt][r] += __shfl_xor(p1[mt][r], j, 64);
                }
            }
        if (lc == 0) {
            float* part = op.part + ((size_t)blockIdx.y * 2 + wc) * NPTS * 2;
#pragma unroll
            for (int mt = 0; mt < 4; ++mt) {
                const int rowb = r0 + wr * 64 + mt * 16 + half * 4;
#pragma unroll
                for (int r = 0; r < 4; ++r) {
                    part[(size_t)(rowb + r) * 2 + 0] = p0[mt][r];
                    part[(size_t)(rowb + r) * 2 + 1] = p1[mt][r];
                }
            }
        }
        // ---- fused finish: 4th block to complete this bx sums all 8 slots ----
        __syncthreads();                 // all slot stores issued
        if (tid == 0) {
            __threadfence();             // release our part stores
            sdone = __hip_atomic_fetch_add(op.hctr + blockIdx.x, 1,
                                           __ATOMIC_ACQ_REL, __HIP_MEMORY_SCOPE_AGENT);
        }
        __syncthreads();
        if (sdone == 3) {
            __threadfence();             // acquire: see other blocks' slot stores
            const int row = blockIdx.x * 128 + (tid >> 1);
            const int j = tid & 1;
            float a = 0.f;
#pragma unroll
            for (int s = 0; s < 8; ++s)
                a += op.part[(size_t)s * NPTS * 2 + (size_t)row * 2 + j];
            if (j == 0) {
                op.meanp[row] = a + op.bd2[0];
            } else {
                float z = a + op.bd2[1];
                float sp = fmaxf(z, 0.f) + log1pf(expf(-fabsf(z)));
                op.sigmap[row] = fmaf(0.8f, sp, 0.2f);
            }
        }
        return;
    }
#pragma unroll
    for (int nt = 0; nt < 4; ++nt) {
        const int col = c0 + wc * 64 + nt * 16 + lc;
        const float bv = (op.flags & 1) ? op.bias[col] : 0.f;
#pragma unroll
        for (int mt = 0; mt < 4; ++mt) {
            const int rowb = r0 + wr * 64 + mt * 16 + half * 4;
#pragma unroll
            for (int r = 0; r < 4; ++r) {
                float v = acc[mt][nt][r] + bv;
                if (op.flags & 2) v = fmaxf(v, 0.f);
                if (op.flags & 4) v += op.res[(size_t)(rowb + r) * op.ncols + col];
                if (op.flags & 8)  op.outf[(size_t)(rowb + r) * op.ncols + col] = v;
                if (op.flags & 16) op.outb[(size_t)(rowb + r) * op.ncols + col] = f2bf(v);
            }
        }
    }
}

extern "C" void kernel_launch(void* const* d_in, const int* in_sizes, int n_in,
                              void* d_out, int out_size, void* d_ws, size_t ws_size,
                              hipStream_t stream)
{
    (void)in_sizes; (void)n_in; (void)out_size; (void)ws_size;
    const float* c   = (const float*)d_in[0];
    const float* x   = (const float*)d_in[1];
    const float* Wc  = (const float*)d_in[2];
    const float* bc  = (const float*)d_in[3];
    const float* Wa  = (const float*)d_in[4];
    const float* ba  = (const float*)d_in[5];
    const float* Wg1 = (const float*)d_in[6];
    const float* bg1 = (const float*)d_in[7];
    const float* Wg2 = (const float*)d_in[8];
    const float* bg2 = (const float*)d_in[9];
    const float* Wg3 = (const float*)d_in[10];
    const float* bg3 = (const float*)d_in[11];
    const float* Wf1 = (const float*)d_in[12];
    const float* bf1 = (const float*)d_in[13];
    const float* Wf2 = (const float*)d_in[14];
    const float* bf2 = (const float*)d_in[15];
    const float* Wf3 = (const float*)d_in[16];
    const float* bf3 = (const float*)d_in[17];
    const float* Wd1 = (const float*)d_in[18];
    const float* bd1 = (const float*)d_in[19];
    const float* Wd2 = (const float*)d_in[20];
    const float* bd2 = (const float*)d_in[21];

    float* out = (float*)d_out;
    const size_t N = NPTS;
    const size_t SLOT = N * 256;
    float* wsf  = (float*)d_ws;
    int*   nbr  = (int*)d_ws;            // N*16 ints
    float* ew   = wsf + N * 16;          // N*16
    float* dinv = wsf + N * 32;          // N
    float* s0   = wsf + N * 33;          // m1f
    float* s1   = s0 + SLOT;             // g1f -> g2f (in place)
    float* s2   = s1 + SLOT;             // m2f (grid scratch aliased here pre-GEMM)
    unsigned short* b0 = (unsigned short*)(s2 + SLOT);  // m1b -> m3b
    unsigned short* b1 = b0 + SLOT;                     // g1b -> g2b -> g3b
    unsigned short* b2 = b1 + SLOT;                     // hw2b -> hw3b
    unsigned short* b3 = b2 + SLOT;                     // m2b
    unsigned short* wb = b3 + SLOT;
    unsigned short* bWg2 = wb;                          // 256x256 each
    unsigned short* bWf2 = wb + 65536;
    unsigned short* bWg3 = wb + 131072;
    unsigned short* bWf3 = wb + 196608;
    unsigned short* bWd1 = wb + 262144;                 // 512x512
    float* part = (float*)(wb + 262144 + 262144);       // 8 x N x 2 fp32 head partials
    int* hctr   = (int*)(part + 8 * N * 2);             // 128 head-finish counters

    // kNN grid scratch aliased into s2 (dead before m2f is written)
    float4* g_pts  = (float4*)s2;                 // NCELL*CAP float4 (4 MB)
    int* g_cnt     = (int*)(s2 + (size_t)NCELL * CAP * 4);  // NCELL ints

    float* o_mean  = out;
    float* o_sigma = out + N;
    float* o_g3    = out + 2 * N;
    float* o_m3    = out + 2 * N + N * 256;

    // 1. weight convert+transpose; z=5 plane zeroes cnt (stream-ordered before count)
    wprep_kernel<<<dim3(16, 16, 6), 256, 0, stream>>>(Wg2, Wf2, Wg3, Wf3, Wd1,
                                                      bWg2, bWf2, bWg3, bWf3, bWd1, g_cnt);
    // 2. grid build (single pass, slot buckets); block 0 zeroes head counters
    count_scatter_kernel<<<NPTS / 256, 256, 0, stream>>>((const float2*)c, g_cnt, g_pts, hctr);
    // 3. kNN
    knn_query_kernel<<<NPTS / 4, 256, 0, stream>>>((const float2*)c, g_pts, g_cnt, nbr, ew, dinv);
    // 4. m1 + g1
    init_fused_kernel<<<512, 256, 0, stream>>>(x, (const float2*)c, nbr, ew, dinv,
                                               Wa, ba, Wf1, bf1, Wc, bc, Wg1, bg1,
                                               s0, b0, s1, b1);

    GemmOp z{};
    // 5. layer 2: hw2 (z=0) & m2 (z=1)
    GemmOp ohw2 = z; ohw2.A1 = b1; ohw2.A2 = b1; ohw2.ksplit = 256; ohw2.Wt = bWg2;
    ohw2.ncols = 256; ohw2.Kdim = 256; ohw2.outb = b2; ohw2.flags = 16;
    GemmOp om2 = z; om2.A1 = b0; om2.A2 = b0; om2.ksplit = 256; om2.Wt = bWf2;
    om2.ncols = 256; om2.Kdim = 256; om2.bias = bf2; om2.res = s0;
    om2.outf = s2; om2.outb = b3; om2.flags = 31;
    gemm_bf16_kernel<<<dim3(NPTS / 128, 2, 2), 256, 0, stream>>>(ohw2, om2);
    // 6. g2 = g1 + relu(agg(hw2) + b_g2) -> s1 (in place) + b1
    agg_kernel<<<NPTS / 8, 256, 0, stream>>>(b2, nbr, ew, dinv, bg2, s1, s1, b1);

    // 7. layer 3: hw3 (z=0) & m3 (z=1)
    GemmOp ohw3 = z; ohw3.A1 = b1; ohw3.A2 = b1; ohw3.ksplit = 256; ohw3.Wt = bWg3;
    ohw3.ncols = 256; ohw3.Kdim = 256; ohw3.outb = b2; ohw3.flags = 16;
    GemmOp om3 = z; om3.A1 = b3; om3.A2 = b3; om3.ksplit = 256; om3.Wt = bWf3;
    om3.ncols = 256; om3.Kdim = 256; om3.bias = bf3; om3.res = s2;
    om3.outf = o_m3; om3.outb = b0; om3.flags = 31;
    gemm_bf16_kernel<<<dim3(NPTS / 128, 2, 2), 256, 0, stream>>>(ohw3, om3);
    // 8. g3 = g2 + relu(agg(hw3) + b_g3) -> o_g3 + b1
    agg_kernel<<<NPTS / 8, 256, 0, stream>>>(b2, nbr, ew, dinv, bg3, s1, o_g3, b1);

    // 9. head: h = relu([g3|m3]@W_d1 + b_d1); partial h@W_d2 -> part slots;
    //    last block per bx fuses the finish (mean/sigma)
    GemmOp oh = z; oh.A1 = b1; oh.A2 = b0; oh.ksplit = 256; oh.Wt = bWd1;
    oh.ncols = 512; oh.Kdim = 512; oh.bias = bd1; oh.Wd2 = Wd2; oh.part = part;
    oh.hctr = hctr; oh.meanp = o_mean; oh.sigmap = o_sigma; oh.bd2 = bd2;
    oh.flags = 32;
    gemm_bf16_kernel<<<dim3(NPTS / 128, 4, 1), 256, 0, stream>>>(oh, oh);
}

// Round 4
// 274.181 us; speedup vs baseline: 1.0973x; 1.0914x over previous
//
#include <hip/hip_runtime.h>
#include <math.h>

#define NPTS 16384
#define KNN 16
#define GRES 128                 // grid cells per axis
#define NCELL (GRES * GRES)
#define CAP 16                   // slots per cell (Poisson(1): P(>16) ~ 1e-14)

typedef unsigned long long ull;
typedef __attribute__((ext_vector_type(8))) short  bf16x8;
typedef __attribute__((ext_vector_type(4))) float  f32x4;

__device__ inline unsigned short f2bf(float f) {
    unsigned int u = __float_as_uint(f);
    u += 0x7fffu + ((u >> 16) & 1u);          // round-to-nearest-even
    return (unsigned short)(u >> 16);
}
__device__ inline float bf2f(unsigned short u) {
    return __uint_as_float(((unsigned int)u) << 16);
}

// async 16B global->LDS DMA (wave-uniform LDS base + lane*16; dest must be linear)
__device__ inline void glds16(const void* g, void* l) {
    __builtin_amdgcn_global_load_lds((const __attribute__((address_space(1))) void*)g,
                                     (__attribute__((address_space(3))) void*)l, 16, 0, 0);
}

// NOTE (journal): two structural fusions were tried and REVERTED:
//  - knn+wprep single launch (round 2): ~neutral.
//  - head-GEMM fused finish via agent-scope atomic+threadfence (rounds 2-3):
//    +24 us — the release/acquire fences force per-XCD L2 writeback/invalidate
//    (L2s not cross-coherent); gemm dispatches ballooned 8->47 us (MfmaUtil 6%).
//    Cross-block result handoff MUST stay dispatch-ordered on this chip.

// ------- weight prep: W (K x Ncol fp32) -> Wt (Ncol x K bf16); z=5 plane zeroes cnt -------
__global__ __launch_bounds__(256) void wprep_kernel(
    const float* __restrict__ W0, const float* __restrict__ W1,
    const float* __restrict__ W2, const float* __restrict__ W3,
    const float* __restrict__ W4,
    unsigned short* __restrict__ D0, unsigned short* __restrict__ D1,
    unsigned short* __restrict__ D2, unsigned short* __restrict__ D3,
    unsigned short* __restrict__ D4, int* __restrict__ cnt)
{
    const int z = blockIdx.z;
    if (z == 5) {
        const int i = (blockIdx.y * 16 + blockIdx.x) * 256 + threadIdx.x;
        if (i < NCELL) cnt[i] = 0;
        return;
    }
    const float* W; unsigned short* D; int K;
    if (z == 0) { W = W0; D = D0; K = 256; }
    else if (z == 1) { W = W1; D = D1; K = 256; }
    else if (z == 2) { W = W2; D = D2; K = 256; }
    else if (z == 3) { W = W3; D = D3; K = 256; }
    else { W = W4; D = D4; K = 512; }
    const int nt = K / 32;
    if (blockIdx.x >= nt || blockIdx.y >= nt) return;
    const int k0 = blockIdx.x * 32, n0 = blockIdx.y * 32;
    __shared__ float t[32][33];
    const int tr = threadIdx.x >> 5, tc = threadIdx.x & 31;
#pragma unroll
    for (int i = 0; i < 4; ++i)
        t[tr + i * 8][tc] = W[(size_t)(k0 + tr + i * 8) * K + n0 + tc];
    __syncthreads();
#pragma unroll
    for (int i = 0; i < 4; ++i)
        D[(size_t)(n0 + tr + i * 8) * K + k0 + tc] = f2bf(t[tc][tr + i * 8]);
}

// ---------------- count+scatter in one pass (slot buckets) ----------------
__global__ __launch_bounds__(256) void count_scatter_kernel(const float2* __restrict__ c,
    int* __restrict__ cnt, float4* __restrict__ pts)
{
    const int i = blockIdx.x * 256 + threadIdx.x;
    float2 p = c[i];
    int cx = min(GRES - 1, max(0, (int)(p.x * GRES)));
    int cy = min(GRES - 1, max(0, (int)(p.y * GRES)));
    int cell = cy * GRES + cx;
    int slot = atomicAdd(&cnt[cell], 1);
    if (slot < CAP) {
        float4 v;
        v.x = p.x; v.y = p.y; v.z = __uint_as_float((unsigned int)i); v.w = 0.f;
        pts[cell * CAP + slot] = v;
    }
}

// -------- kNN query: one wave per query, bitonic top-16 across lanes --------
// ALL shuffles execute with full EXEC (shuffle reads from disabled lanes
// return 0 -> shuffles must never sit under divergent control flow).
__global__ __launch_bounds__(256) void knn_query_kernel(const float2* __restrict__ c,
    const float4* __restrict__ pts, const int* __restrict__ cnt,
    int* __restrict__ nbr, float* __restrict__ ew, float* __restrict__ dinv)
{
    const int lane = threadIdx.x & 63;
    const int qidx = blockIdx.x * 4 + (threadIdx.x >> 6);
    const float2 qc = c[qidx];
    const float qx = qc.x, qy = qc.y;
    const int qcx = min(GRES - 1, max(0, (int)(qx * GRES)));
    const int qcy = min(GRES - 1, max(0, (int)(qy * GRES)));

    ull cur = ~0ULL;   // lanes 0..15 will hold top-16 ascending; others INF

    auto process = [&](int ccy, int ccx, bool valid) {
        int s0 = 0, len = 0;
        if (valid && ccy >= 0 && ccy < GRES && ccx >= 0 && ccx < GRES) {
            const int cell = ccy * GRES + ccx;
            s0 = cell * CAP;
            len = min(cnt[cell], CAP);
        }
        int pin = len;                       // inclusive prefix over lanes (full exec)
#pragma unroll
        for (int off = 1; off < 64; off <<= 1) {
            int v = __shfl_up(pin, off, 64);
            pin += (lane >= off) ? v : 0;
        }
        const int T = __shfl(pin, 63, 64);
        const int pex = pin - len;
        for (int b = 0; b < T; b += 64) {
            const int ci = b + lane;
            const int cq = min(ci, T - 1);   // clamp so every lane runs uniformly
            int lo = 0, hi = 63;             // smallest h with pin[h] > cq
#pragma unroll
            for (int it = 0; it < 6; ++it) {
                const int mid = (lo + hi) >> 1;
                const int pm = __shfl(pin, mid, 64);   // full exec
                if (pm > cq) hi = mid; else lo = mid + 1;
            }
            const int cs = __shfl(s0, hi, 64);         // full exec
            const int cb = __shfl(pex, hi, 64);        // full exec
            const int p  = cs + (cq - cb);             // valid slot index for all lanes
            const float4 pp = pts[p];
            const float dx = pp.x - qx, dy = pp.y - qy;
            const float d2 = fmaf(dx, dx, dy * dy);
            const int pidx = (int)__float_as_uint(pp.z);
            ull key = ~0ULL;
            if (ci < T && pidx != qidx)
                key = (((ull)__float_as_uint(d2)) << 32) | (ull)__float_as_uint(pp.z);
            // bitonic sort, 64 lanes ascending (full exec)
#pragma unroll
            for (int k = 2; k <= 64; k <<= 1) {
#pragma unroll
                for (int j = k >> 1; j > 0; j >>= 1) {
                    ull o = __shfl_xor(key, j, 64);
                    bool takeMin = (((lane & k) == 0) == ((lane & j) == 0));
                    ull mn = (o < key) ? o : key;
                    ull mx = (o > key) ? o : key;
                    key = takeMin ? mn : mx;
                }
            }
            // merge: cur(asc, lanes0-15) ++ batch-top16 reversed (lanes16-31)
            ull rev = __shfl(key, (31 - lane) & 63, 64);   // full exec, hoisted
            ull val = (lane < 16) ? cur : ((lane < 32) ? rev : ~0ULL);
#pragma unroll
            for (int j = 16; j > 0; j >>= 1) {
                ull o = __shfl_xor(val, j, 64);
                ull mn = (o < val) ? o : val;
                ull mx = (o > val) ? o : val;
                val = ((lane & j) == 0) ? mn : mx;
            }
            cur = (lane < 16) ? val : ~0ULL;
        }
    };

    // initial 7x7 window (49 cells)
    process(qcy - 3 + lane / 7, qcx - 3 + (lane % 7), lane < 49);

    int R = 3;
    const float h = 1.0f / GRES;
    while (true) {
        ull k15 = __shfl(cur, 15, 64);
        float dmax = __uint_as_float((unsigned int)(k15 >> 32)); // NaN if unfilled
        float rr = 0.999f * (float)R * h;
        if (dmax < rr * rr) break;        // NaN -> false -> expand
        if (R >= GRES) break;
        ++R;
        const int ncells = 8 * R;
        for (int cc = 0; cc < ncells; cc += 64) {
            const int i = cc + lane;
            int ccy = 0, ccx = 0;
            const bool valid = (i < ncells);
            if (valid) {
                const int side = 2 * R + 1;
                if (i < side)            { ccy = qcy - R; ccx = qcx - R + i; }
                else if (i < 2 * side)   { ccy = qcy + R; ccx = qcx - R + (i - side); }
                else {
                    const int j = i - 2 * side;
                    ccy = qcy - R + 1 + (j >> 1);
                    ccx = (j & 1) ? (qcx + R) : (qcx - R);
                }
            }
            process(ccy, ccx, valid);
        }
    }

    // epilogue: lanes 0..15 hold the exact top-16 (ascending keys)
    float w = 0.f; int nb = 0;
    if (lane < 16) {
        nb = (int)(cur & 0xffffffffu);
        float d2 = __uint_as_float((unsigned int)(cur >> 32));
        w = expf(-0.5f * sqrtf(d2));
    }
    float acc = w;
#pragma unroll
    for (int off = 1; off < 64; off <<= 1) acc += __shfl_xor(acc, off, 64);
    if (lane < 16) {
        nbr[qidx * KNN + lane] = nb;
        ew[qidx * KNN + lane]  = w;
    }
    if (lane == 0) dinv[qidx] = 1.0f / sqrtf(1.0f + acc);
}

// ----- fused: blocks [0,256): m1 = (x@Wa+ba)+relu(x@Wf1+bf1); [256,512): g1 -----
__global__ __launch_bounds__(256) void init_fused_kernel(
    const float* __restrict__ x, const float2* __restrict__ c,
    const int* __restrict__ nbr, const float* __restrict__ ew, const float* __restrict__ dinv,
    const float* __restrict__ Wa, const float* __restrict__ ba,
    const float* __restrict__ Wf, const float* __restrict__ bf,
    const float* __restrict__ Wc, const float* __restrict__ bc,
    const float* __restrict__ Wg, const float* __restrict__ bg,
    float* __restrict__ m1f, unsigned short* __restrict__ m1b,
    float* __restrict__ g1f, unsigned short* __restrict__ g1b)
{
    __shared__ float smem[64 * 32];
    const int tid = threadIdx.x;
    if (blockIdx.x < 256) {
        const int i0 = blockIdx.x * 64;
#pragma unroll
        for (int it = 0; it < 8; ++it)
            smem[tid + it * 256] = x[(size_t)i0 * 32 + tid + it * 256];
        float wa[32], wf[32];
#pragma unroll
        for (int k = 0; k < 32; ++k) { wa[k] = Wa[k * 256 + tid]; wf[k] = Wf[k * 256 + tid]; }
        const float b0 = ba[tid], b1 = bf[tid];
        __syncthreads();
        for (int r = 0; r < 64; ++r) {
            float a0 = b0, a1 = b1;
#pragma unroll
            for (int k = 0; k < 32; ++k) {
                float xv = smem[r * 32 + k];
                a0 = fmaf(xv, wa[k], a0);
                a1 = fmaf(xv, wf[k], a1);
            }
            const float v = a0 + fmaxf(a1, 0.0f);
            m1f[(size_t)(i0 + r) * 256 + tid] = v;
            m1b[(size_t)(i0 + r) * 256 + tid] = f2bf(v);
        }
    } else {
        float (*su)[5] = (float(*)[5])smem;
        const int i0 = (blockIdx.x - 256) * 64;
        if (tid < 64) {
            const int i = i0 + tid;
            float ux = 0.f, uy = 0.f;
            for (int t = 0; t < KNN; ++t) {
                int nb = nbr[i * KNN + t];
                float w = ew[i * KNN + t] * dinv[nb];
                float2 cn = c[nb];
                ux = fmaf(w, cn.x, ux); uy = fmaf(w, cn.y, uy);
            }
            float di = dinv[i];
            float2 ci = c[i];
            ux = fmaf(di, ci.x, ux); uy = fmaf(di, ci.y, uy);
            su[tid][0] = ux; su[tid][1] = uy; su[tid][2] = ci.x; su[tid][3] = ci.y; su[tid][4] = di;
        }
        __syncthreads();
        const float wc0 = Wc[tid], wc1 = Wc[256 + tid];
        const float wg0 = Wg[tid], wg1 = Wg[256 + tid];
        const float bcj = bc[tid], bgj = bg[tid];
        for (int r = 0; r < 64; ++r) {
            float ux = su[r][0], uy = su[r][1], cx = su[r][2], cy = su[r][3], di = su[r][4];
            float coords0 = fmaf(cx, wc0, fmaf(cy, wc1, bcj));
            float pre = fmaf(di, fmaf(ux, wg0, uy * wg1), bgj);
            const float v = coords0 + fmaxf(pre, 0.0f);
            g1f[(size_t)(i0 + r) * 256 + tid] = v;
            g1b[(size_t)(i0 + r) * 256 + tid] = f2bf(v);
        }
    }
}

// ---------- GCN aggregate (vectorized bf16x8 gather): out = res + relu(b + di*(sum + di*hw_i)) ----------
// 8 rows x 32 col-groups per block; each thread owns 8 consecutive cols (16B loads).
// Half-wave (32 lanes) reads one full 512B hw row contiguously per gather.
// bias/res loads issued BEFORE the gather loop so they overlap gather latency.
__global__ __launch_bounds__(256) void agg_kernel(const unsigned short* __restrict__ hw,
    const int* __restrict__ nbr, const float* __restrict__ ew, const float* __restrict__ dinv,
    const float* __restrict__ bias, const float* __restrict__ res,
    float* __restrict__ outf, unsigned short* __restrict__ outb)
{
    __shared__ int   sn[8][16];
    __shared__ float sw[8][16];
    __shared__ float sdi[8];
    const int tid = threadIdx.x;
    const int i0  = blockIdx.x * 8;
    if (tid < 128) {
        const int r = tid >> 4, t = tid & 15;
        const int i = i0 + r;
        const int nb = nbr[i * KNN + t];
        sn[r][t] = nb;
        sw[r][t] = ew[i * KNN + t] * dinv[nb];
        if (t == 0) sdi[r] = dinv[i];
    }
    __syncthreads();
    const int rl = tid >> 5;          // row within block (broadcast LDS reads, free)
    const int c0 = (tid & 31) * 8;    // 8-col group
    const int i  = i0 + rl;
    const float di = sdi[rl];
    float bb[8], rv[8];
    *(float4*)&bb[0] = *(const float4*)&bias[c0];
    *(float4*)&bb[4] = *(const float4*)&bias[c0 + 4];
    *(float4*)&rv[0] = *(const float4*)&res[(size_t)i * 256 + c0];
    *(float4*)&rv[4] = *(const float4*)&res[(size_t)i * 256 + c0 + 4];
    float acc[8];
    {
        const bf16x8 h = *(const bf16x8*)&hw[(size_t)i * 256 + c0];
#pragma unroll
        for (int e = 0; e < 8; ++e) acc[e] = di * bf2f((unsigned short)h[e]);
    }
#pragma unroll
    for (int t = 0; t < KNN; ++t) {
        const float w = sw[rl][t];
        const bf16x8 h = *(const bf16x8*)&hw[(size_t)sn[rl][t] * 256 + c0];
#pragma unroll
        for (int e = 0; e < 8; ++e) acc[e] = fmaf(w, bf2f((unsigned short)h[e]), acc[e]);
    }
    float vo[8];
    bf16x8 ob;
#pragma unroll
    for (int e = 0; e < 8; ++e) {
        float v = fmaf(di, acc[e], bb[e]);
        v = rv[e] + fmaxf(v, 0.0f);
        vo[e] = v;
        ob[e] = (short)f2bf(v);
    }
    *(float4*)&outf[(size_t)i * 256 + c0]     = *(const float4*)&vo[0];
    *(float4*)&outf[(size_t)i * 256 + c0 + 4] = *(const float4*)&vo[4];
    *(bf16x8*)&outb[(size_t)i * 256 + c0] = ob;
}

// -------- bf16 MFMA GEMM, dual-op (blockIdx.z selects) + head-reduce mode --------
// A row-stride 256 bf16 (split A1|A2 at ksplit). Wt pre-transposed bf16 [n][Kdim].
// Tile 128x128, BK=64, 4 waves (2x2), wave = 4x4 of 16x16x32. fp32 accumulate.
// Staging: double-buffered LDS via global_load_lds width=16 (async DMA). LDS dest
// LINEAR (glds requirement); k-slot XOR swizzle slot' = slot ^ (row&7) applied on
// the SOURCE address and mirrored on the ds_read side (<=2-way alias, free m136).
// LDS = 64KB -> 2 blocks/CU = the full 512-block grid co-resident.
// flags: 1=+bias 2=relu 4=+res(fp32) 8=write outf 16=write outb
//        32=head-reduce: partial h@Wd2 -> part[(blockIdx.y*2+wc)][row][2]
//        (slot per column-half wave: waves wc=0/1 share rows -> separate slots)
struct GemmOp {
    const unsigned short *A1, *A2; int ksplit;
    const unsigned short *Wt; int ncols, Kdim;
    const float *bias; const float *res;
    float *outf; unsigned short *outb;
    const float *Wd2; float *part;
    int flags;
};
__global__ __launch_bounds__(256) void gemm_bf16_kernel(GemmOp opA, GemmOp opB)
{
    const GemmOp op = (blockIdx.z == 0) ? opA : opB;
    __shared__ unsigned short As[2][128 * 64];
    __shared__ unsigned short Bs[2][128 * 64];
    const int tid = threadIdx.x;
    const int r0 = blockIdx.x * 128;
    const int c0 = blockIdx.y * 128;
    const int w  = tid >> 6;
    const int wr = w >> 1, wc = w & 1;
    const int l  = tid & 63;
    const int half = l >> 4, lc = l & 15;

    f32x4 acc[4][4];
#pragma unroll
    for (int mt = 0; mt < 4; ++mt)
#pragma unroll
        for (int nt = 0; nt < 4; ++nt) acc[mt][nt] = (f32x4){0.f, 0.f, 0.f, 0.f};

    // stage one 128x64 A-tile + 128x64 B-tile into buffer b (k-origin k0).
    // linear LDS dest (byte = g*16), source k-slot = (g&7) ^ (row&7).
    auto stage = [&](int b, int k0) {
        const unsigned short* Asrc = (k0 < op.ksplit) ? (op.A1 + k0) : (op.A2 + (k0 - op.ksplit));
        const unsigned short* Bsrc = op.Wt + k0;
#pragma unroll
        for (int it = 0; it < 4; ++it) {
            const int g = tid + it * 256;
            const int r = g >> 3;
            const int s = (g & 7) ^ (r & 7);
            glds16(Asrc + (size_t)(r0 + r) * 256 + s * 8, &As[b][g * 8]);
        }
#pragma unroll
        for (int it = 0; it < 4; ++it) {
            const int g = tid + it * 256;
            const int r = g >> 3;
            const int s = (g & 7) ^ (r & 7);
            glds16(Bsrc + (size_t)(c0 + r) * op.Kdim + s * 8, &Bs[b][g * 8]);
        }
    };

    const int NT = op.Kdim >> 6;
    stage(0, 0);
    __syncthreads();                     // compiler drains vmcnt(0): tile 0 resident
    int cur = 0;
    for (int t = 0; t < NT; ++t) {
        if (t + 1 < NT) stage(cur ^ 1, (t + 1) << 6);   // async, in flight during MFMA
#pragma unroll
        for (int ks = 0; ks < 2; ++ks) {                // k order identical to BK=32 version
            bf16x8 af[4], bq[4];
#pragma unroll
            for (int mt = 0; mt < 4; ++mt) {
                const int rr = wr * 64 + mt * 16 + lc;
                af[mt] = *(const bf16x8*)&As[cur][rr * 64 + ((((ks << 2) + half) ^ (rr & 7)) << 3)];
            }
#pragma unroll
            for (int nt = 0; nt < 4; ++nt) {
                const int rr = wc * 64 + nt * 16 + lc;
                bq[nt] = *(const bf16x8*)&Bs[cur][rr * 64 + ((((ks << 2) + half) ^ (rr & 7)) << 3)];
            }
#pragma unroll
            for (int mt = 0; mt < 4; ++mt)
#pragma unroll
                for (int nt = 0; nt < 4; ++nt)
                    acc[mt][nt] = __builtin_amdgcn_mfma_f32_16x16x32_bf16(af[mt], bq[nt], acc[mt][nt], 0, 0, 0);
        }
        if (t + 1 < NT) { __syncthreads(); cur ^= 1; }  // drain = next tile ready
    }

    // C/D layout: col=lane&15, row=(lane>>4)*4+reg
    if (op.flags & 32) {
        // head-reduce: v = relu(acc+bias); partial dot with Wd2 -> per-(by,wc) slot
        float p0[4][4], p1[4][4];
#pragma unroll
        for (int mt = 0; mt < 4; ++mt)
#pragma unroll
            for (int r = 0; r < 4; ++r) { p0[mt][r] = 0.f; p1[mt][r] = 0.f; }
#pragma unroll
        for (int nt = 0; nt < 4; ++nt) {
            const int col = c0 + wc * 64 + nt * 16 + lc;
            const float bv = op.bias[col];
            const float w0 = op.Wd2[col * 2 + 0];
            const float w1 = op.Wd2[col * 2 + 1];
#pragma unroll
            for (int mt = 0; mt < 4; ++mt)
#pragma unroll
                for (int r = 0; r < 4; ++r) {
                    float v = fmaxf(acc[mt][nt][r] + bv, 0.f);
                    p0[mt][r] = fmaf(v, w0, p0[mt][r]);
                    p1[mt][r] = fmaf(v, w1, p1[mt][r]);
                }
        }
        // reduce over the 16 lanes (lc) sharing each row; full-exec shuffles
#pragma unroll
        for (int mt = 0; mt < 4; ++mt)
#pragma unroll
            for (int r = 0; r < 4; ++r) {
#pragma unroll
                for (int j = 1; j < 16; j <<= 1) {
                    p0[mt][r] += __shfl_xor(p0[mt][r], j, 64);
                    p1[mt][r] += __shfl_xor(p1[mt][r], j, 64);
                }
            }
        if (lc == 0) {
            float* part = op.part + ((size_t)blockIdx.y * 2 + wc) * NPTS * 2;
#pragma unroll
            for (int mt = 0; mt < 4; ++mt) {
                const int rowb = r0 + wr * 64 + mt * 16 + half * 4;
#pragma unroll
                for (int r = 0; r < 4; ++r) {
                    part[(size_t)(rowb + r) * 2 + 0] = p0[mt][r];
                    part[(size_t)(rowb + r) * 2 + 1] = p1[mt][r];
                }
            }
        }
        return;
    }
#pragma unroll
    for (int nt = 0; nt < 4; ++nt) {
        const int col = c0 + wc * 64 + nt * 16 + lc;
        const float bv = (op.flags & 1) ? op.bias[col] : 0.f;
#pragma unroll
        for (int mt = 0; mt < 4; ++mt) {
            const int rowb = r0 + wr * 64 + mt * 16 + half * 4;
#pragma unroll
            for (int r = 0; r < 4; ++r) {
                float v = acc[mt][nt][r] + bv;
                if (op.flags & 2) v = fmaxf(v, 0.f);
                if (op.flags & 4) v += op.res[(size_t)(rowb + r) * op.ncols + col];
                if (op.flags & 8)  op.outf[(size_t)(rowb + r) * op.ncols + col] = v;
                if (op.flags & 16) op.outb[(size_t)(rowb + r) * op.ncols + col] = f2bf(v);
            }
        }
    }
}

// ---------------- finish: mean/sigma from 8 head partial slots ----------------
__global__ __launch_bounds__(256) void finish_kernel(const float* __restrict__ part,
    const float* __restrict__ b, float* __restrict__ mean, float* __restrict__ sigma)
{
    const int i = blockIdx.x * 256 + threadIdx.x;
    float a0 = 0.f, a1 = 0.f;
#pragma unroll
    for (int j = 0; j < 8; ++j) {
        a0 += part[(size_t)j * NPTS * 2 + 2 * i];
        a1 += part[(size_t)j * NPTS * 2 + 2 * i + 1];
    }
    mean[i] = a0 + b[0];
    float z = a1 + b[1];
    float sp = fmaxf(z, 0.f) + log1pf(expf(-fabsf(z)));
    sigma[i] = fmaf(0.8f, sp, 0.2f);
}

extern "C" void kernel_launch(void* const* d_in, const int* in_sizes, int n_in,
                              void* d_out, int out_size, void* d_ws, size_t ws_size,
                              hipStream_t stream)
{
    (void)in_sizes; (void)n_in; (void)out_size; (void)ws_size;
    const float* c   = (const float*)d_in[0];
    const float* x   = (const float*)d_in[1];
    const float* Wc  = (const float*)d_in[2];
    const float* bc  = (const float*)d_in[3];
    const float* Wa  = (const float*)d_in[4];
    const float* ba  = (const float*)d_in[5];
    const float* Wg1 = (const float*)d_in[6];
    const float* bg1 = (const float*)d_in[7];
    const float* Wg2 = (const float*)d_in[8];
    const float* bg2 = (const float*)d_in[9];
    const float* Wg3 = (const float*)d_in[10];
    const float* bg3 = (const float*)d_in[11];
    const float* Wf1 = (const float*)d_in[12];
    const float* bf1 = (const float*)d_in[13];
    const float* Wf2 = (const float*)d_in[14];
    const float* bf2 = (const float*)d_in[15];
    const float* Wf3 = (const float*)d_in[16];
    const float* bf3 = (const float*)d_in[17];
    const float* Wd1 = (const float*)d_in[18];
    const float* bd1 = (const float*)d_in[19];
    const float* Wd2 = (const float*)d_in[20];
    const float* bd2 = (const float*)d_in[21];

    float* out = (float*)d_out;
    const size_t N = NPTS;
    const size_t SLOT = N * 256;
    float* wsf  = (float*)d_ws;
    int*   nbr  = (int*)d_ws;            // N*16 ints
    float* ew   = wsf + N * 16;          // N*16
    float* dinv = wsf + N * 32;          // N
    float* s0   = wsf + N * 33;          // m1f
    float* s1   = s0 + SLOT;             // g1f -> g2f (in place)
    float* s2   = s1 + SLOT;             // m2f (grid scratch aliased here pre-GEMM)
    unsigned short* b0 = (unsigned short*)(s2 + SLOT);  // m1b -> m3b
    unsigned short* b1 = b0 + SLOT;                     // g1b -> g2b -> g3b
    unsigned short* b2 = b1 + SLOT;                     // hw2b -> hw3b
    unsigned short* b3 = b2 + SLOT;                     // m2b
    unsigned short* wb = b3 + SLOT;
    unsigned short* bWg2 = wb;                          // 256x256 each
    unsigned short* bWf2 = wb + 65536;
    unsigned short* bWg3 = wb + 131072;
    unsigned short* bWf3 = wb + 196608;
    unsigned short* bWd1 = wb + 262144;                 // 512x512
    float* part = (float*)(wb + 262144 + 262144);       // 8 x N x 2 fp32 head partials

    // kNN grid scratch aliased into s2 (dead before m2f is written)
    float4* g_pts  = (float4*)s2;                 // NCELL*CAP float4 (4 MB)
    int* g_cnt     = (int*)(s2 + (size_t)NCELL * CAP * 4);  // NCELL ints

    float* o_mean  = out;
    float* o_sigma = out + N;
    float* o_g3    = out + 2 * N;
    float* o_m3    = out + 2 * N + N * 256;

    // 1. weight convert+transpose; z=5 plane zeroes cnt (stream-ordered before count)
    wprep_kernel<<<dim3(16, 16, 6), 256, 0, stream>>>(Wg2, Wf2, Wg3, Wf3, Wd1,
                                                      bWg2, bWf2, bWg3, bWf3, bWd1, g_cnt);
    // 2. grid build (single pass, slot buckets)
    count_scatter_kernel<<<NPTS / 256, 256, 0, stream>>>((const float2*)c, g_cnt, g_pts);
    // 3. kNN
    knn_query_kernel<<<NPTS / 4, 256, 0, stream>>>((const float2*)c, g_pts, g_cnt, nbr, ew, dinv);
    // 4. m1 + g1
    init_fused_kernel<<<512, 256, 0, stream>>>(x, (const float2*)c, nbr, ew, dinv,
                                               Wa, ba, Wf1, bf1, Wc, bc, Wg1, bg1,
                                               s0, b0, s1, b1);

    GemmOp z{};
    // 5. layer 2: hw2 (z=0) & m2 (z=1)
    GemmOp ohw2 = z; ohw2.A1 = b1; ohw2.A2 = b1; ohw2.ksplit = 256; ohw2.Wt = bWg2;
    ohw2.ncols = 256; ohw2.Kdim = 256; ohw2.outb = b2; ohw2.flags = 16;
    GemmOp om2 = z; om2.A1 = b0; om2.A2 = b0; om2.ksplit = 256; om2.Wt = bWf2;
    om2.ncols = 256; om2.Kdim = 256; om2.bias = bf2; om2.res = s0;
    om2.outf = s2; om2.outb = b3; om2.flags = 31;
    gemm_bf16_kernel<<<dim3(NPTS / 128, 2, 2), 256, 0, stream>>>(ohw2, om2);
    // 6. g2 = g1 + relu(agg(hw2) + b_g2) -> s1 (in place) + b1
    agg_kernel<<<NPTS / 8, 256, 0, stream>>>(b2, nbr, ew, dinv, bg2, s1, s1, b1);

    // 7. layer 3: hw3 (z=0) & m3 (z=1)
    GemmOp ohw3 = z; ohw3.A1 = b1; ohw3.A2 = b1; ohw3.ksplit = 256; ohw3.Wt = bWg3;
    ohw3.ncols = 256; ohw3.Kdim = 256; ohw3.outb = b2; ohw3.flags = 16;
    GemmOp om3 = z; om3.A1 = b3; om3.A2 = b3; om3.ksplit = 256; om3.Wt = bWf3;
    om3.ncols = 256; om3.Kdim = 256; om3.bias = bf3; om3.res = s2;
    om3.outf = o_m3; om3.outb = b0; om3.flags = 31;
    gemm_bf16_kernel<<<dim3(NPTS / 128, 2, 2), 256, 0, stream>>>(ohw3, om3);
    // 8. g3 = g2 + relu(agg(hw3) + b_g3) -> o_g3 + b1
    agg_kernel<<<NPTS / 8, 256, 0, stream>>>(b2, nbr, ew, dinv, bg3, s1, o_g3, b1);

    // 9. head: h = relu([g3|m3]@W_d1 + b_d1); partial h@W_d2 -> part slots
    GemmOp oh = z; oh.A1 = b1; oh.A2 = b0; oh.ksplit = 256; oh.Wt = bWd1;
    oh.ncols = 512; oh.Kdim = 512; oh.bias = bd1; oh.Wd2 = Wd2; oh.part = part;
    oh.flags = 32;
    gemm_bf16_kernel<<<dim3(NPTS / 128, 4, 1), 256, 0, stream>>>(oh, oh);
    // 10. mean / sigma
    finish_kernel<<<NPTS / 256, 256, 0, stream>>>(part, bd2, o_mean, o_sigma);
}